// Round 6
// baseline (827.397 us; speedup 1.0000x reference)
//
#include <hip/hip_runtime.h>
#include <hip/hip_bf16.h>
#include <stdint.h>

typedef __attribute__((ext_vector_type(8))) short short8;
typedef __attribute__((ext_vector_type(4))) short short4v;
typedef __attribute__((ext_vector_type(4))) float floatx4;
typedef __attribute__((ext_vector_type(2))) float floatx2;

#define B_TOT 1024
#define N_TOK 128
#define C_DIM 128
#define NHEAD 8
#define NW_MASK 64

// ---- workspace layout (bytes) ----
// BIAS: [8][128][128] fp32
// WALL: per head slot 30720 (image 30464): wq[3][16][136]us|wk[3][16][136]us|wv[16][136]us
// WPT : per pair 9216: [128n][36]us (stride 36 kills the old 8-way conflict)
#define BIAS_OFF 0
#define WALL_OFF 524288
#define WHEAD_SLOT 30720
#define WPT_OFF 770048          // 524288 + 8*30720
#define WS_BYTES 806912

// ---- LDS layout (bytes), total 80896 -> 2 blocks/CU ----
#define QS_LDS 0                // [128][18] fp32  q rows (consumer splits)   9216
#define KS_LDS 9216             // [128][56] bf16  [kh|km|kl]                14336
#define VS_LDS 23552            // [128][16] fp32  v                          8192
#define XO_LDS 31744            // [128][36] bf16  attn out                   9216
#define WB_LDS 40960            // 30720  W single buffer
#define WPT_LDS 71680           // 9216   Wproj^T single buffer
#define LDS_BYTES 80896

#define MFMA(a, b, c) __builtin_amdgcn_mfma_f32_16x16x32_bf16((a), (b), (c), 0, 0, 0)

__device__ __forceinline__ float bf2f(ushort u) {
  union { uint32_t u; float f; } v; v.u = ((uint32_t)u) << 16; return v.f;
}
__device__ __forceinline__ ushort f2bf(float f) {
  uint32_t u = __float_as_uint(f);
  return (ushort)((u + 0x7FFFu + ((u >> 16) & 1u)) >> 16);  // RNE
}
__device__ __forceinline__ void split3(float f, ushort& h, ushort& m, ushort& l) {
  h = f2bf(f);  float r  = f - bf2f(h);
  m = f2bf(r);  float r2 = r - bf2f(m);
  l = f2bf(r2);
}
__device__ __forceinline__ void split3t(float f, ushort& h, ushort& m, ushort& l) {
  h = (ushort)(__float_as_uint(f) >> 16);
  float r  = f - bf2f(h);
  m = (ushort)(__float_as_uint(r) >> 16);
  float r2 = r - bf2f(m);
  l = f2bf(r2);
}

// async 16B/lane global->LDS DMA
__device__ __forceinline__ void dma16(const void* g, void* l_) {
  __builtin_amdgcn_global_load_lds((const __attribute__((address_space(1))) void*)g,
                                   (__attribute__((address_space(3))) void*)l_,
                                   16, 0, 0);
}

// ---------------------------------------------------------------------------
// Prologue: bias gather + all weight splits, once; W in the padded LDS image.
// ---------------------------------------------------------------------------
__global__ __launch_bounds__(512)
void prep_kernel(const int* __restrict__ rel_index, const float* __restrict__ table,
                 const float* __restrict__ Wq, const float* __restrict__ Wkv,
                 const float* __restrict__ Wproj, char* __restrict__ ws) {
  float*  bias_g = (float*)(ws + BIAS_OFF);
  ushort* wpt_g  = (ushort*)(ws + WPT_OFF);

  int idx = blockIdx.x * 512 + threadIdx.x;
  if (idx < 131072) {
    int h = idx >> 14, mn = idx & 16383;
    bias_g[idx] = table[rel_index[mn] * NHEAD + h];
  } else if (idx < 131072 + 16384) {
    int t = idx - 131072;                 // h*2048 + oc*128 + kk
    int h = t >> 11, r = t & 2047, oc = r >> 7, kk = r & 127;
    ushort a, bb, cc;
    split3(Wq[kk * C_DIM + h * 16 + oc] * 0.25f, a, bb, cc);
    ushort* wqp = (ushort*)(ws + WALL_OFF + h * WHEAD_SLOT);
    wqp[0 * 2176 + oc * 136 + kk] = a;
    wqp[1 * 2176 + oc * 136 + kk] = bb;
    wqp[2 * 2176 + oc * 136 + kk] = cc;
  } else if (idx < 131072 + 2 * 16384) {
    int t = idx - 131072 - 16384;
    int h = t >> 11, r = t & 2047, oc = r >> 7, kk = r & 127;
    ushort a, bb, cc;
    split3(Wkv[kk * (2 * C_DIM) + h * 16 + oc], a, bb, cc);
    ushort* wkp = (ushort*)(ws + WALL_OFF + h * WHEAD_SLOT) + 6528;
    wkp[0 * 2176 + oc * 136 + kk] = a;
    wkp[1 * 2176 + oc * 136 + kk] = bb;
    wkp[2 * 2176 + oc * 136 + kk] = cc;
  } else if (idx < 131072 + 3 * 16384) {
    int t = idx - 131072 - 2 * 16384;
    int h = t >> 11, r = t & 2047, oc = r >> 7, kk = r & 127;
    ushort* wvp = (ushort*)(ws + WALL_OFF + h * WHEAD_SLOT) + 13056;
    wvp[oc * 136 + kk] = f2bf(Wkv[kk * (2 * C_DIM) + C_DIM + h * 16 + oc]);
  } else if (idx < 131072 + 4 * 16384) {
    int t = idx - 131072 - 3 * 16384;     // hp*4096 + n*32 + kk
    int hp = t >> 12, r = t & 4095, n = r >> 5, kk = r & 31;
    wpt_g[hp * 4608 + n * 36 + kk] = f2bf(Wproj[(hp * 32 + kk) * C_DIM + n]);
  }
}

// ---------------------------------------------------------------------------
// Fused window attention. 512 threads = 8 waves; wave w owns rows 16w..16w+15.
// vs round 5: LDS cut to 80896 B (single-buffered W/WPT, q stored fp32 with
// consumer-side split, tightened pads, WPT 8-way conflict fixed) and
// __launch_bounds__(512,4) -> 64 arch + 64 acc regs -> 2 blocks/CU.
// 2 barriers/head; W(h+1) DMA issued after barA (drains at barB); WPT pair-p
// DMA issued at even h (prev pair's readers finished at barB(h-1)).
// ---------------------------------------------------------------------------
__global__ __launch_bounds__(512, 4)
void wattn_kernel(const float* __restrict__ x, const float* __restrict__ mask,
                  const float* __restrict__ bproj, const char* __restrict__ ws,
                  float* __restrict__ out) {
  extern __shared__ char smem[];
  float*  qs_f = (float*)(smem + QS_LDS);
  ushort* ks   = (ushort*)(smem + KS_LDS);
  float*  vs   = (float*)(smem + VS_LDS);
  ushort* xo   = (ushort*)(smem + XO_LDS);

  const float* bias_g = (const float*)(ws + BIAS_OFF);

  const int tid  = threadIdx.x;
  const int w    = tid >> 6;
  const int l    = tid & 63;
  const int quad = l >> 4;
  const int c    = l & 15;
  const int b    = blockIdx.x;
  const int wi   = b & (NW_MASK - 1);

  // ---- issue DMA for head-0 W (30 chunks) and pair-0 Wproj^T (9 chunks)
  {
    const char* src = ws + WALL_OFF;
    char* dst = smem + WB_LDS;
    #pragma unroll
    for (int t = 0; t < 4; ++t) {
      int ch = t * 8 + w;
      if (ch < 30) dma16(src + ch * 1024 + l * 16, dst + ch * 1024 + l * 16);
    }
    #pragma unroll
    for (int t = 0; t < 2; ++t) {
      int ch = t * 8 + w;
      if (ch < 9) dma16(ws + WPT_OFF + ch * 1024 + l * 16,
                        smem + WPT_LDS + ch * 1024 + l * 16);
    }
  }

  // ---- split this lane's head-invariant x MFMA A-fragments into registers
  short8 A1[8], A3[8];
  {
    const float* xrow = x + ((size_t)b * N_TOK + 16 * w + c) * C_DIM;
    #pragma unroll
    for (int kt = 0; kt < 8; ++kt) {
      int colb = kt * 16 + (quad & 1) * 8;
      floatx4 xa  = *(const floatx4*)(xrow + colb);
      floatx4 xb2 = *(const floatx4*)(xrow + colb + 4);
      short8 hi8, mi8, lo8;
      #pragma unroll
      for (int jj = 0; jj < 8; ++jj) {
        float f = (jj < 4) ? xa[jj] : xb2[jj - 4];
        ushort hh, mm, ll; split3t(f, hh, mm, ll);
        hi8[jj] = (short)hh; mi8[jj] = (short)mm; lo8[jj] = (short)ll;
      }
      A1[kt] = (quad < 2) ? hi8 : mi8;   // [xh|xm]
      A3[kt] = (quad < 2) ? hi8 : lo8;   // [xh|xl]
    }
  }

  floatx4 oacc[8];
  #pragma unroll
  for (int j = 0; j < 8; ++j) oacc[j] = (floatx4){0.f, 0.f, 0.f, 0.f};

  asm volatile("s_waitcnt vmcnt(0)" ::: "memory");
  __syncthreads();   // head-0 W + pair-0 WPT landed

  for (int h = 0; h < NHEAD; ++h) {
    // ---- phase 2: q,k (6-term split) and v (2-term) projections; B from LDS
    {
      floatx4 aq = (floatx4){0.f,0.f,0.f,0.f};
      floatx4 ak = (floatx4){0.f,0.f,0.f,0.f};
      floatx4 av = (floatx4){0.f,0.f,0.f,0.f};
      const ushort* wh  = (const ushort*)(smem + WB_LDS);
      const ushort* wqp = wh + c * 136;             // plane stride 2176 us
      const ushort* wkp = wh + 6528 + c * 136;
      const ushort* wvp = wh + 13056 + c * 136;
      const int q3off = (quad < 2) ? 2 * 2176 : 0;
      #pragma unroll
      for (int kt = 0; kt < 8; ++kt) {
        int colb = kt * 16 + (quad & 1) * 8;
        short8 bq1 = *(const short8*)(wqp + colb);
        short8 bq2 = *(const short8*)(wqp + 2176 + colb);
        short8 bq3 = *(const short8*)(wqp + q3off + colb);
        aq = MFMA(A1[kt], bq1, aq);  aq = MFMA(A1[kt], bq2, aq);  aq = MFMA(A3[kt], bq3, aq);
        short8 bk1 = *(const short8*)(wkp + colb);
        short8 bk2 = *(const short8*)(wkp + 2176 + colb);
        short8 bk3 = *(const short8*)(wkp + q3off + colb);
        ak = MFMA(A1[kt], bk1, ak);  ak = MFMA(A1[kt], bk2, ak);  ak = MFMA(A3[kt], bk3, ak);
        short8 bv1 = *(const short8*)(wvp + colb);
        av = MFMA(A1[kt], bv1, av);
      }
      #pragma unroll
      for (int i = 0; i < 4; ++i) {
        int tok = 16 * w + 4 * quad + i;
        qs_f[tok * 18 + c] = aq[i];                 // consumer splits
        ushort a, bb, cc;
        split3t(ak[i], a, bb, cc);
        ks[tok * 56 + c] = a; ks[tok * 56 + 16 + c] = bb; ks[tok * 56 + 32 + c] = cc;
        vs[tok * 16 + c] = av[i];
      }
    }
    __syncthreads();   // barA: ks/vs visible; W reads done

    // ---- prefetch next head's W into the (single) buffer; drains at barB
    if (h < 7) {
      const char* src = ws + WALL_OFF + (h + 1) * WHEAD_SLOT;
      char* dst = smem + WB_LDS;
      #pragma unroll
      for (int t = 0; t < 4; ++t) {
        int ch = t * 8 + w;
        if (ch < 30) dma16(src + ch * 1024 + l * 16, dst + ch * 1024 + l * 16);
      }
    }
    // ---- WPT pair (h>>1): prev pair readers finished at barB(h-1)
    if (h >= 2 && !(h & 1)) {
      int p = h >> 1;
      #pragma unroll
      for (int t = 0; t < 2; ++t) {
        int ch = t * 8 + w;
        if (ch < 9) dma16(ws + WPT_OFF + p * 9216 + ch * 1024 + l * 16,
                          smem + WPT_LDS + ch * 1024 + l * 16);
      }
    }

    // ---- phase 3 (fused): logits j-tile -> raw-exp softmax + top-2 fold
    {
      // build aq1/aq3 from fp32 q row (wave-private, no barrier needed)
      short8 aq1, aq3;
      {
        const float* qrowf = qs_f + (16 * w + c) * 18 + (quad & 1) * 8;
        floatx2 qf[4];
        #pragma unroll
        for (int p = 0; p < 4; ++p) qf[p] = *(const floatx2*)(qrowf + 2 * p);
        #pragma unroll
        for (int jj = 0; jj < 8; ++jj) {
          float f = qf[jj >> 1][jj & 1];
          ushort hh, mm, ll; split3t(f, hh, mm, ll);
          aq1[jj] = (short)((quad < 2) ? hh : mm);   // [qh|qm]
          aq3[jj] = (short)((quad < 2) ? hh : ll);   // [qh|ql]
        }
      }

      float m1[4], m2[4], psum[4];
      int   i1[4], i2[4];
      #pragma unroll
      for (int i = 0; i < 4; ++i) {
        m1[i] = -__builtin_inff(); i1[i] = 0;
        m2[i] = -__builtin_inff(); i2[i] = -1;
        psum[i] = 0.0f;
      }

      #pragma unroll
      for (int j = 0; j < 8; ++j) {
        floatx4 acc = (floatx4){0.f, 0.f, 0.f, 0.f};
        const ushort* krow = ks + (16 * j + c) * 56;
        int bo1 = (quad & 1) * 8;
        short8 b1 = *(const short8*)(krow + bo1);            // [kh|kh]
        short8 b2 = *(const short8*)(krow + 16 + bo1);       // [km|km]
        short8 b3 = *(const short8*)(krow + ((quad < 2) ? 32 + quad * 8
                                                        : (quad - 2) * 8)); // [kl|kh]
        acc = MFMA(aq1, b1, acc);
        acc = MFMA(aq1, b2, acc);
        acc = MFMA(aq3, b3, acc);

        #pragma unroll
        for (int i = 0; i < 4; ++i) {
          int m = 16 * w + 4 * quad + i;
          int n = 16 * j + c;
          float v = acc[i] + bias_g[(h * N_TOK + m) * N_TOK + n] +
                             mask[(wi * N_TOK + m) * N_TOK + n];
          psum[i] += __expf(v);           // raw exp: independent, fp32-safe
          int col = 16 * j + c;
          bool g1 = v > m1[i];
          bool g2 = (!g1) && (v > m2[i]);
          m2[i] = g1 ? m1[i] : (g2 ? v : m2[i]);
          i2[i] = g1 ? i1[i] : (g2 ? col : i2[i]);
          m1[i] = g1 ? v : m1[i];
          i1[i] = g1 ? col : i1[i];
        }
      }

      // ---- cross-lane reduce over the 16 columns held by the quad's lanes
      #pragma unroll
      for (int i = 0; i < 4; ++i) {
        float M1 = m1[i], M2 = m2[i], PS = psum[i];
        int I1 = i1[i], I2 = i2[i];
        #pragma unroll
        for (int d = 1; d < 16; d <<= 1) {
          float om1 = __shfl_xor(M1, d); int oi1 = __shfl_xor(I1, d);
          float om2 = __shfl_xor(M2, d); int oi2 = __shfl_xor(I2, d);
          float ops = __shfl_xor(PS, d);
          bool aw = (M1 > om1) || (M1 == om1 && I1 < oi1);
          float lv = aw ? om1 : M1;  int li = aw ? oi1 : I1;
          float sv = aw ? M2 : om2;  int si = aw ? I2 : oi2;
          M1 = aw ? M1 : om1;  I1 = aw ? I1 : oi1;
          bool sb = (sv > lv) || (sv == lv && si < li);
          M2 = sb ? sv : lv; I2 = sb ? si : li;
          PS += ops;
        }
        float inv = 1.0f / PS;
        float p1 = __expf(M1) * inv;
        float p2 = __expf(M2) * inv;
        int tok = 16 * w + 4 * quad + i;
        float o = p1 * vs[I1 * 16 + c] + p2 * vs[I2 * 16 + c];
        xo[tok * 36 + (h & 1) * 16 + c] = f2bf(o);  // wave-private rows
      }
    }

    // ---- phase 4: out-projection, K=32 per head pair, persistent acc
    if (h & 1) {
      const ushort* wpt_l = (const ushort*)(smem + WPT_LDS);
      int row = 16 * w + c;
      short4v alo = *(const short4v*)(xo + row * 36 + quad * 8);
      short4v ahi = *(const short4v*)(xo + row * 36 + quad * 8 + 4);
      short8 a = __builtin_shufflevector(alo, ahi, 0, 1, 2, 3, 4, 5, 6, 7);
      #pragma unroll
      for (int j = 0; j < 8; ++j) {
        const ushort* wr = wpt_l + (16 * j + c) * 36 + quad * 8;
        short4v blo = *(const short4v*)(wr);
        short4v bhi = *(const short4v*)(wr + 4);
        short8 bf = __builtin_shufflevector(blo, bhi, 0, 1, 2, 3, 4, 5, 6, 7);
        oacc[j] = MFMA(a, bf, oacc[j]);
      }
    }

    if (h < 7) __syncthreads();   // barB: drains DMAs; ks/vs/W safe to overwrite
  }

  // ---- epilogue: + bproj, fp32 store
  #pragma unroll
  for (int j = 0; j < 8; ++j) {
    float bp = bproj[16 * j + c];
    #pragma unroll
    for (int i = 0; i < 4; ++i) {
      int row = 16 * w + 4 * quad + i;
      out[((size_t)b * N_TOK + row) * C_DIM + 16 * j + c] = oacc[j][i] + bp;
    }
  }
}

extern "C" void kernel_launch(void* const* d_in, const int* in_sizes, int n_in,
                              void* d_out, int out_size, void* d_ws, size_t ws_size,
                              hipStream_t stream) {
  const float* x     = (const float*)d_in[0];
  const float* mask  = (const float*)d_in[1];
  const float* Wq    = (const float*)d_in[2];
  const float* Wkv   = (const float*)d_in[3];
  const float* Wproj = (const float*)d_in[4];
  const float* bproj = (const float*)d_in[5];
  const float* btab  = (const float*)d_in[6];
  const int*   ridx  = (const int*)d_in[7];
  float* outp = (float*)d_out;
  char*  ws   = (char*)d_ws;

  (void)in_sizes; (void)n_in; (void)out_size; (void)ws_size;

  hipFuncSetAttribute(reinterpret_cast<const void*>(wattn_kernel),
                      hipFuncAttributeMaxDynamicSharedMemorySize, LDS_BYTES);

  // 131072 bias + 4*16384 weight-split tasks = 196608 -> 384 blocks
  prep_kernel<<<384, 512, 0, stream>>>(ridx, btab, Wq, Wkv, Wproj, ws);
  wattn_kernel<<<B_TOT, 512, LDS_BYTES, stream>>>(x, mask, bproj, ws, outp);
}

// Round 7
// 353.390 us; speedup vs baseline: 2.3413x; 2.3413x over previous
//
#include <hip/hip_runtime.h>
#include <hip/hip_bf16.h>
#include <stdint.h>

typedef __attribute__((ext_vector_type(8))) short short8;
typedef __attribute__((ext_vector_type(4))) float floatx4;

#define B_TOT 1024
#define N_TOK 128
#define C_DIM 128
#define NHEAD 8
#define NW_MASK 64

// ---- workspace layout (bytes) ----
// BIAS: [8][128][128] fp32
// WALL: per head slot 30720 (image 30464): wq[3][16][136]us|wk[3][16][136]us|wv[16][136]us
// WPT : per pair 10240: [128n][40]us  (stride 40: b128-aligned, 2-way banks)
#define BIAS_OFF 0
#define WALL_OFF 524288
#define WHEAD_SLOT 30720
#define WPT_OFF 770048          // 524288 + 8*30720
#define WS_BYTES 811008

// ---- LDS layout (bytes), total 152576 ----
#define QS_LDS 0                // [128][56] bf16  [qh|qm|ql]       14336
#define KS_LDS 14336            // 2 x [128][56] bf16               28672 (dbuf)
#define VS_LDS 43008            // 2 x [128][17] fp32               17408 (dbuf)
#define XO_LDS 60416            // [128][40] bf16                   10240
#define WB_LDS 70656            // 2 x 30720  W double-buffer       61440
#define WPTB_LDS 132096         // 2 x 10240  Wproj^T double-buffer 20480
#define LDS_BYTES 152576

#define MFMA(a, b, c) __builtin_amdgcn_mfma_f32_16x16x32_bf16((a), (b), (c), 0, 0, 0)

__device__ __forceinline__ float bf2f(ushort u) {
  union { uint32_t u; float f; } v; v.u = ((uint32_t)u) << 16; return v.f;
}
__device__ __forceinline__ ushort f2bf(float f) {
  uint32_t u = __float_as_uint(f);
  return (ushort)((u + 0x7FFFu + ((u >> 16) & 1u)) >> 16);  // RNE
}
__device__ __forceinline__ void split3(float f, ushort& h, ushort& m, ushort& l) {
  h = f2bf(f);  float r  = f - bf2f(h);
  m = f2bf(r);  float r2 = r - bf2f(m);
  l = f2bf(r2);
}
__device__ __forceinline__ void split3t(float f, ushort& h, ushort& m, ushort& l) {
  h = (ushort)(__float_as_uint(f) >> 16);
  float r  = f - bf2f(h);
  m = (ushort)(__float_as_uint(r) >> 16);
  float r2 = r - bf2f(m);
  l = f2bf(r2);
}

// async 16B/lane global->LDS DMA
__device__ __forceinline__ void dma16(const void* g, void* l_) {
  __builtin_amdgcn_global_load_lds((const __attribute__((address_space(1))) void*)g,
                                   (__attribute__((address_space(3))) void*)l_,
                                   16, 0, 0);
}

// DPP ROW_ROR cross-lane (row = 16 lanes): VALU-pipe, no LDS traffic.
template <int CTRL>
__device__ __forceinline__ float dppf(float x) {
  return __int_as_float(__builtin_amdgcn_update_dpp(0, __float_as_int(x),
                                                    CTRL, 0xF, 0xF, true));
}
template <int CTRL>
__device__ __forceinline__ int dppi(int x) {
  return __builtin_amdgcn_update_dpp(0, x, CTRL, 0xF, 0xF, true);
}

// ---------------------------------------------------------------------------
// Prologue: bias gather + all weight splits, once; W in the padded LDS image.
// ---------------------------------------------------------------------------
__global__ __launch_bounds__(512)
void prep_kernel(const int* __restrict__ rel_index, const float* __restrict__ table,
                 const float* __restrict__ Wq, const float* __restrict__ Wkv,
                 const float* __restrict__ Wproj, char* __restrict__ ws) {
  float*  bias_g = (float*)(ws + BIAS_OFF);
  ushort* wpt_g  = (ushort*)(ws + WPT_OFF);

  int idx = blockIdx.x * 512 + threadIdx.x;
  if (idx < 131072) {
    int h = idx >> 14, mn = idx & 16383;
    bias_g[idx] = table[rel_index[mn] * NHEAD + h];
  } else if (idx < 131072 + 16384) {
    int t = idx - 131072;                 // h*2048 + oc*128 + kk
    int h = t >> 11, r = t & 2047, oc = r >> 7, kk = r & 127;
    ushort a, bb, cc;
    split3(Wq[kk * C_DIM + h * 16 + oc] * 0.25f, a, bb, cc);
    ushort* wqp = (ushort*)(ws + WALL_OFF + h * WHEAD_SLOT);
    wqp[0 * 2176 + oc * 136 + kk] = a;
    wqp[1 * 2176 + oc * 136 + kk] = bb;
    wqp[2 * 2176 + oc * 136 + kk] = cc;
  } else if (idx < 131072 + 2 * 16384) {
    int t = idx - 131072 - 16384;
    int h = t >> 11, r = t & 2047, oc = r >> 7, kk = r & 127;
    ushort a, bb, cc;
    split3(Wkv[kk * (2 * C_DIM) + h * 16 + oc], a, bb, cc);
    ushort* wkp = (ushort*)(ws + WALL_OFF + h * WHEAD_SLOT) + 6528;
    wkp[0 * 2176 + oc * 136 + kk] = a;
    wkp[1 * 2176 + oc * 136 + kk] = bb;
    wkp[2 * 2176 + oc * 136 + kk] = cc;
  } else if (idx < 131072 + 3 * 16384) {
    int t = idx - 131072 - 2 * 16384;
    int h = t >> 11, r = t & 2047, oc = r >> 7, kk = r & 127;
    ushort* wvp = (ushort*)(ws + WALL_OFF + h * WHEAD_SLOT) + 13056;
    wvp[oc * 136 + kk] = f2bf(Wkv[kk * (2 * C_DIM) + C_DIM + h * 16 + oc]);
  } else if (idx < 131072 + 4 * 16384) {
    int t = idx - 131072 - 3 * 16384;     // hp*4096 + n*32 + kk
    int hp = t >> 12, r = t & 4095, n = r >> 5, kk = r & 31;
    wpt_g[hp * 5120 + n * 40 + kk] = f2bf(Wproj[(hp * 32 + kk) * C_DIM + n]);
  }
}

// ---------------------------------------------------------------------------
// Fused window attention. 512 threads = 8 waves; wave w owns rows 16w..16w+15.
// = round-5 structure (311 us) + two LDS-pipe fixes:
//   (a) 16-lane softmax/top-2 butterfly via DPP ROW_ROR (VALU pipe) instead of
//       __shfl_xor (ds_swizzle on the CU-shared LDS pipe): -640 LDS ops/head.
//   (b) Wproj^T stride 32 -> 40 us (was an 8-way bank conflict, now 2-way,
//       still one aligned ds_read_b128 per fragment).
// Occupancy is register-bound at 2 waves/SIMD (A1/A3=64 VGPR + oacc 32 AGPR);
// (512,4) proven to spill in rounds 1 & 6 -- do not revisit.
// ---------------------------------------------------------------------------
__global__ __launch_bounds__(512, 2)
void wattn_kernel(const float* __restrict__ x, const float* __restrict__ mask,
                  const float* __restrict__ bproj, const char* __restrict__ ws,
                  float* __restrict__ out) {
  extern __shared__ char smem[];
  ushort* qs = (ushort*)(smem + QS_LDS);
  ushort* xo = (ushort*)(smem + XO_LDS);

  const float* bias_g = (const float*)(ws + BIAS_OFF);

  const int tid  = threadIdx.x;
  const int w    = tid >> 6;
  const int l    = tid & 63;
  const int quad = l >> 4;
  const int c    = l & 15;
  const int b    = blockIdx.x;
  const int wi   = b & (NW_MASK - 1);

  // ---- issue DMA for head-0 W (30 chunks) and pair-0 Wproj^T (10 chunks)
  {
    const char* src = ws + WALL_OFF;
    char* dst = smem + WB_LDS;
    #pragma unroll
    for (int t = 0; t < 4; ++t) {
      int ch = t * 8 + w;
      if (ch < 30) dma16(src + ch * 1024 + l * 16, dst + ch * 1024 + l * 16);
    }
    #pragma unroll
    for (int t = 0; t < 2; ++t) {
      int ch = t * 8 + w;
      if (ch < 10) dma16(ws + WPT_OFF + ch * 1024 + l * 16,
                         smem + WPTB_LDS + ch * 1024 + l * 16);
    }
  }

  // ---- split this lane's head-invariant x MFMA A-fragments into registers
  short8 A1[8], A3[8];
  {
    const float* xrow = x + ((size_t)b * N_TOK + 16 * w + c) * C_DIM;
    #pragma unroll
    for (int kt = 0; kt < 8; ++kt) {
      int colb = kt * 16 + (quad & 1) * 8;
      floatx4 xa  = *(const floatx4*)(xrow + colb);
      floatx4 xb2 = *(const floatx4*)(xrow + colb + 4);
      short8 hi8, mi8, lo8;
      #pragma unroll
      for (int jj = 0; jj < 8; ++jj) {
        float f = (jj < 4) ? xa[jj] : xb2[jj - 4];
        ushort hh, mm, ll; split3t(f, hh, mm, ll);
        hi8[jj] = (short)hh; mi8[jj] = (short)mm; lo8[jj] = (short)ll;
      }
      A1[kt] = (quad < 2) ? hi8 : mi8;   // [xh|xm]
      A3[kt] = (quad < 2) ? hi8 : lo8;   // [xh|xl]
    }
  }

  floatx4 oacc[8];
  #pragma unroll
  for (int j = 0; j < 8; ++j) oacc[j] = (floatx4){0.f, 0.f, 0.f, 0.f};

  asm volatile("s_waitcnt vmcnt(0)" ::: "memory");
  __syncthreads();   // head-0 W + pair-0 WPT landed

  for (int h = 0; h < NHEAD; ++h) {
    ushort* ks_c = (ushort*)(smem + KS_LDS + (h & 1) * 14336);
    float*  vs_c = (float*)(smem + VS_LDS + (h & 1) * 8704);

    // ---- prefetch next head's W (and next pair's Wproj^T) into the other buf
    if (h < 7) {
      const char* src = ws + WALL_OFF + (h + 1) * WHEAD_SLOT;
      char* dst = smem + WB_LDS + ((h + 1) & 1) * 30720;
      #pragma unroll
      for (int t = 0; t < 4; ++t) {
        int ch = t * 8 + w;
        if (ch < 30) dma16(src + ch * 1024 + l * 16, dst + ch * 1024 + l * 16);
      }
      if (h & 1) {
        int np = (h + 1) >> 1;           // next pair
        #pragma unroll
        for (int t = 0; t < 2; ++t) {
          int ch = t * 8 + w;
          if (ch < 10) dma16(ws + WPT_OFF + np * 10240 + ch * 1024 + l * 16,
                             smem + WPTB_LDS + (np & 1) * 10240 + ch * 1024 + l * 16);
        }
      }
    }

    // ---- phase 2: q,k (6-term split) and v (2-term) projections; B from LDS
    {
      floatx4 aq = (floatx4){0.f,0.f,0.f,0.f};
      floatx4 ak = (floatx4){0.f,0.f,0.f,0.f};
      floatx4 av = (floatx4){0.f,0.f,0.f,0.f};
      const ushort* wh  = (const ushort*)(smem + WB_LDS + (h & 1) * 30720);
      const ushort* wqp = wh + c * 136;             // plane stride 2176 us
      const ushort* wkp = wh + 6528 + c * 136;
      const ushort* wvp = wh + 13056 + c * 136;
      const int q3off = (quad < 2) ? 2 * 2176 : 0;
      #pragma unroll
      for (int kt = 0; kt < 8; ++kt) {
        int colb = kt * 16 + (quad & 1) * 8;
        short8 bq1 = *(const short8*)(wqp + colb);
        short8 bq2 = *(const short8*)(wqp + 2176 + colb);
        short8 bq3 = *(const short8*)(wqp + q3off + colb);
        aq = MFMA(A1[kt], bq1, aq);  aq = MFMA(A1[kt], bq2, aq);  aq = MFMA(A3[kt], bq3, aq);
        short8 bk1 = *(const short8*)(wkp + colb);
        short8 bk2 = *(const short8*)(wkp + 2176 + colb);
        short8 bk3 = *(const short8*)(wkp + q3off + colb);
        ak = MFMA(A1[kt], bk1, ak);  ak = MFMA(A1[kt], bk2, ak);  ak = MFMA(A3[kt], bk3, ak);
        short8 bv1 = *(const short8*)(wvp + colb);
        av = MFMA(A1[kt], bv1, av);
      }
      #pragma unroll
      for (int i = 0; i < 4; ++i) {
        int tok = 16 * w + 4 * quad + i;
        ushort a, bb, cc;
        split3t(aq[i], a, bb, cc);
        qs[tok * 56 + c] = a; qs[tok * 56 + 16 + c] = bb; qs[tok * 56 + 32 + c] = cc;
        split3t(ak[i], a, bb, cc);
        ks_c[tok * 56 + c] = a; ks_c[tok * 56 + 16 + c] = bb; ks_c[tok * 56 + 32 + c] = cc;
        vs_c[tok * 17 + c] = av[i];
      }
    }
    __syncthreads();   // the ONLY barrier this head; also drains prefetch DMA

    // ---- phase 3 (fused): logits j-tile -> raw-exp softmax + top-2 fold
    {
      const ushort* qrow = qs + (16 * w + c) * 56;
      short8 aq1 = *(const short8*)(qrow + quad * 8);                      // [qh|qm]
      short8 aq3 = *(const short8*)(qrow + ((quad < 2) ? quad * 8 : 16 + quad * 8)); // [qh|ql]

      float m1[4], m2[4], psum[4];
      int   i1[4], i2[4];
      #pragma unroll
      for (int i = 0; i < 4; ++i) {
        m1[i] = -__builtin_inff(); i1[i] = 0;
        m2[i] = -__builtin_inff(); i2[i] = -1;
        psum[i] = 0.0f;
      }

      #pragma unroll
      for (int j = 0; j < 8; ++j) {
        floatx4 acc = (floatx4){0.f, 0.f, 0.f, 0.f};
        const ushort* krow = ks_c + (16 * j + c) * 56;
        int bo1 = (quad & 1) * 8;
        short8 b1 = *(const short8*)(krow + bo1);            // [kh|kh]
        short8 b2 = *(const short8*)(krow + 16 + bo1);       // [km|km]
        short8 b3 = *(const short8*)(krow + ((quad < 2) ? 32 + quad * 8
                                                        : (quad - 2) * 8)); // [kl|kh]
        acc = MFMA(aq1, b1, acc);
        acc = MFMA(aq1, b2, acc);
        acc = MFMA(aq3, b3, acc);

        #pragma unroll
        for (int i = 0; i < 4; ++i) {
          int m = 16 * w + 4 * quad + i;
          int n = 16 * j + c;
          float v = acc[i] + bias_g[(h * N_TOK + m) * N_TOK + n] +
                             mask[(wi * N_TOK + m) * N_TOK + n];
          psum[i] += __expf(v);           // raw exp: independent, fp32-safe
          int col = 16 * j + c;
          bool g1 = v > m1[i];
          bool g2 = (!g1) && (v > m2[i]);
          m2[i] = g1 ? m1[i] : (g2 ? v : m2[i]);
          i2[i] = g1 ? i1[i] : (g2 ? col : i2[i]);
          m1[i] = g1 ? v : m1[i];
          i1[i] = g1 ? col : i1[i];
        }
      }

      // ---- cross-lane reduce over the quad's 16 lanes via DPP ROW_ROR.
      // Rotation steps 1,2,4,8 merge DISJOINT windows -> exact for the
      // associative+commutative (top2, psum) merge; all 16 lanes converge.
      #pragma unroll
      for (int i = 0; i < 4; ++i) {
        float M1 = m1[i], M2 = m2[i], PS = psum[i];
        int I1 = i1[i], I2 = i2[i];

        #define RSTEP(CTRL)                                                   \
        {                                                                     \
          float om1 = dppf<CTRL>(M1); int oi1 = dppi<CTRL>(I1);               \
          float om2 = dppf<CTRL>(M2); int oi2 = dppi<CTRL>(I2);               \
          float ops = dppf<CTRL>(PS);                                         \
          bool aw = (M1 > om1) || (M1 == om1 && I1 < oi1);                    \
          float lv = aw ? om1 : M1;  int li = aw ? oi1 : I1;                  \
          float sv = aw ? M2 : om2;  int si = aw ? I2 : oi2;                  \
          M1 = aw ? M1 : om1;  I1 = aw ? I1 : oi1;                            \
          bool sb = (sv > lv) || (sv == lv && si < li);                       \
          M2 = sb ? sv : lv; I2 = sb ? si : li;                               \
          PS += ops;                                                          \
        }
        RSTEP(0x121)   // row_ror:1
        RSTEP(0x122)   // row_ror:2
        RSTEP(0x124)   // row_ror:4
        RSTEP(0x128)   // row_ror:8
        #undef RSTEP

        float inv = 1.0f / PS;
        float p1 = __expf(M1) * inv;
        float p2 = __expf(M2) * inv;
        int tok = 16 * w + 4 * quad + i;
        float o = p1 * vs_c[I1 * 17 + c] + p2 * vs_c[I2 * 17 + c];
        xo[tok * 40 + (h & 1) * 16 + c] = f2bf(o);
      }
    }

    // ---- phase 4: out-projection, K=32 per head pair, persistent acc
    if (h & 1) {
      const ushort* wptp = (const ushort*)(smem + WPTB_LDS + ((h >> 1) & 1) * 10240);
      short8 a = *(const short8*)(xo + (16 * w + c) * 40 + quad * 8);
      #pragma unroll
      for (int j = 0; j < 8; ++j) {
        short8 bf = *(const short8*)(wptp + (16 * j + c) * 40 + quad * 8);
        oacc[j] = MFMA(a, bf, oacc[j]);
      }
    }
  }

  // ---- epilogue: + bproj, fp32 store
  #pragma unroll
  for (int j = 0; j < 8; ++j) {
    float bp = bproj[16 * j + c];
    #pragma unroll
    for (int i = 0; i < 4; ++i) {
      int row = 16 * w + 4 * quad + i;
      out[((size_t)b * N_TOK + row) * C_DIM + 16 * j + c] = oacc[j][i] + bp;
    }
  }
}

extern "C" void kernel_launch(void* const* d_in, const int* in_sizes, int n_in,
                              void* d_out, int out_size, void* d_ws, size_t ws_size,
                              hipStream_t stream) {
  const float* x     = (const float*)d_in[0];
  const float* mask  = (const float*)d_in[1];
  const float* Wq    = (const float*)d_in[2];
  const float* Wkv   = (const float*)d_in[3];
  const float* Wproj = (const float*)d_in[4];
  const float* bproj = (const float*)d_in[5];
  const float* btab  = (const float*)d_in[6];
  const int*   ridx  = (const int*)d_in[7];
  float* outp = (float*)d_out;
  char*  ws   = (char*)d_ws;

  (void)in_sizes; (void)n_in; (void)out_size; (void)ws_size;

  hipFuncSetAttribute(reinterpret_cast<const void*>(wattn_kernel),
                      hipFuncAttributeMaxDynamicSharedMemorySize, LDS_BYTES);

  // 131072 bias + 4*16384 weight-split tasks = 196608 -> 384 blocks
  prep_kernel<<<384, 512, 0, stream>>>(ridx, btab, Wq, Wkv, Wproj, ws);
  wattn_kernel<<<B_TOT, 512, LDS_BYTES, stream>>>(x, mask, bproj, ws, outp);
}